// Round 1
// baseline (1205.964 us; speedup 1.0000x reference)
//
#include <hip/hip_runtime.h>

// WindowAttention: B=4096 windows, N=49 tokens, DIM=384, H=12 heads, D=32.
// Pipeline: convert_x -> prep(weights^T bf16 + bias in MFMA-frag layout) ->
//           qkv_gemm (bf16 MFMA) -> attention (MFMA, poly-norm) -> proj_gemm.
// WS layout (bytes):
//   [0,154140672)          x_bf16  (77,070,336 bf16)  -- later aliased by O
//   [154140672,308281344)  q       [B,H,49,32] bf16
//   [308281344,462422016)  k       [B,H,49,32] bf16
//   [462422016,616562688)  v       [B,H,49,32] bf16
//   [616562688,617447424)  w_qkv^T [1152,384] bf16
//   [617447424,617742336)  w_proj^T[384,384]  bf16
//   [617742336,617938944)  bias-init frags [12][4][4][256] f32 (bias/SCALE, C-layout)
// Requires ws_size >= ~618 MB.

using s16x8 = __attribute__((ext_vector_type(8))) short;
using f32x4 = __attribute__((ext_vector_type(4))) float;

#define AS1 __attribute__((address_space(1)))
#define AS3 __attribute__((address_space(3)))

__device__ __forceinline__ short f2bf(float f) {
  unsigned int u = __float_as_uint(f);
  u += 0x7fffu + ((u >> 16) & 1u);          // round-to-nearest-even
  return (short)(u >> 16);
}

__device__ __forceinline__ void load16_to_lds(const void* g, void* l) {
  __builtin_amdgcn_global_load_lds((AS1 void*)(void*)g, (AS3 void*)l, 16, 0, 0);
}

// ---------------- kernel 1: x fp32 -> bf16 ----------------
__global__ __launch_bounds__(256) void convert_x(const float* __restrict__ x,
                                                 short* __restrict__ xb) {
  int i = blockIdx.x * 256 + threadIdx.x;    // 9,633,792 threads, 8 elems each
  const float4* xv = (const float4*)x;
  float4 a = xv[2 * i];
  float4 c = xv[2 * i + 1];
  s16x8 o;
  o[0] = f2bf(a.x); o[1] = f2bf(a.y); o[2] = f2bf(a.z); o[3] = f2bf(a.w);
  o[4] = f2bf(c.x); o[5] = f2bf(c.y); o[6] = f2bf(c.z); o[7] = f2bf(c.w);
  ((s16x8*)xb)[i] = o;
}

// ---------------- kernel 2: weights^T + bias frags ----------------
__global__ __launch_bounds__(256) void prep(const float* __restrict__ wqkv,
                                            const float* __restrict__ wproj,
                                            const float* __restrict__ btab,
                                            const int* __restrict__ rel,
                                            short* __restrict__ wqt,
                                            short* __restrict__ wpt,
                                            float* __restrict__ bini) {
  int i = blockIdx.x * 256 + threadIdx.x;
  if (i < 442368) {                      // w_qkv^T [1152][384]
    int c = i / 384, kx = i - c * 384;
    wqt[i] = f2bf(wqkv[kx * 1152 + c]);
  } else if (i < 442368 + 147456) {      // w_proj^T [384][384]
    int j = i - 442368;
    int c = j / 384, kx = j - c * 384;
    wpt[j] = f2bf(wproj[kx * 384 + c]);
  } else if (i < 442368 + 147456 + 49152) {
    int j = i - (442368 + 147456);       // [head][fi][fj][lane*4+r]
    int head = j >> 12;
    int rem = j & 4095;
    int fi = rem >> 10; int rem2 = rem & 1023;
    int fj = rem2 >> 8; int rem3 = rem2 & 255;
    int l = rem3 >> 2;  int r = rem3 & 3;
    int row = fi * 16 + (l >> 4) * 4 + r;   // query index
    int col = fj * 16 + (l & 15);           // key index
    float val = 0.f;
    if (row < 49 && col < 49)
      val = btab[rel[row * 49 + col] * 12 + head] * 5.656854249492381f; // /SCALE
    bini[j] = val;
  }
}

// ---------------- kernel 3: QKV GEMM  [200704,384] @ [384,1152] ----------------
__global__ __launch_bounds__(256) void gemm_qkv(const short* __restrict__ A,
                                                const short* __restrict__ Bt,
                                                short* __restrict__ q,
                                                short* __restrict__ k,
                                                short* __restrict__ v) {
  __shared__ __align__(16) short As[2][128 * 32];
  __shared__ __align__(16) short Bs[2][128 * 32];
  const int t = threadIdx.x;
  const int wave = t >> 6, lane = t & 63;
  const int quad = lane >> 4, l15 = lane & 15;
  const int wm = wave & 1, wn = wave >> 1;
  const int m0 = blockIdx.y * 128;
  const int n0 = blockIdx.x * 128;

  auto stage = [&](int buf, int kt) {
#pragma unroll
    for (int p = 0; p < 2; ++p) {
      int o = p * 4096 + wave * 1024 + lane * 16;  // byte offset in 8 KB tile
      int row = o >> 6, colb = o & 63;
      load16_to_lds((const char*)A + (size_t)(m0 + row) * 768 + kt * 64 + colb,
                    (char*)(&As[buf][0]) + o);
      load16_to_lds((const char*)Bt + (size_t)(n0 + row) * 768 + kt * 64 + colb,
                    (char*)(&Bs[buf][0]) + o);
    }
  };

  f32x4 acc[4][4] = {};
  stage(0, 0);
  for (int kt = 0; kt < 12; ++kt) {
    __syncthreads();
    if (kt + 1 < 12) stage((kt + 1) & 1, kt + 1);
    const short* as = &As[kt & 1][0];
    const short* bs = &Bs[kt & 1][0];
    s16x8 af[4], bfr[4];
#pragma unroll
    for (int i = 0; i < 4; ++i)
      af[i] = *(const s16x8*)(as + (wm * 64 + i * 16 + l15) * 32 + quad * 8);
#pragma unroll
    for (int j = 0; j < 4; ++j)
      bfr[j] = *(const s16x8*)(bs + (wn * 64 + j * 16 + l15) * 32 + quad * 8);
#pragma unroll
    for (int i = 0; i < 4; ++i)
#pragma unroll
      for (int j = 0; j < 4; ++j)
        acc[i][j] = __builtin_amdgcn_mfma_f32_16x16x32_bf16(af[i], bfr[j], acc[i][j], 0, 0, 0);
  }

  // epilogue: scatter into q/k/v [B,H,49,32] bf16
  const int part = n0 / 384;                       // block lies in one part
  short* dst = (part == 0) ? q : ((part == 1) ? k : v);
  const int cb = (n0 - part * 384) + wn * 64 + l15;
#pragma unroll
  for (int i = 0; i < 4; ++i) {
#pragma unroll
    for (int r = 0; r < 4; ++r) {
      int m = m0 + wm * 64 + i * 16 + quad * 4 + r;
      int b = m / 49;
      int n = m - b * 49;
      int base = b * 18816 + n * 32;               // b*12*49*32 + n*32
#pragma unroll
      for (int j = 0; j < 4; ++j) {
        int c = cb + j * 16;
        int h = c >> 5, d = c & 31;
        dst[base + h * 1568 + d] = f2bf(acc[i][j][r]);
      }
    }
  }
}

// ---------------- kernel 4: attention, one wave per (window, head) ----------------
__global__ __launch_bounds__(256) void attn(const short* __restrict__ q,
                                            const short* __restrict__ k,
                                            const short* __restrict__ v,
                                            const float* __restrict__ biasinit,
                                            short* __restrict__ O) {
  __shared__ __align__(16) short smem[4 * 6912];   // per wave: VT 32x72, P 64x72
  const int t = threadIdx.x, wave = t >> 6, lane = t & 63;
  const int quad = lane >> 4, l15 = lane & 15;
  const int wid = blockIdx.x;                      // 0..12287
  const int b = wid / 3;
  const int head = (wid - 3 * b) * 4 + wave;
  short* VT = smem + wave * 6912;
  short* P = VT + 2304;
  const size_t hb = ((size_t)b * 12 + head) * 1568;
  const short* qh = q + hb;
  const short* kh = k + hb;
  const short* vh = v + hb;

  // S accumulator initialized with bias/SCALE in C-fragment layout
  f32x4 acc[4][4];
  const float* bi = biasinit + head * 4096;
#pragma unroll
  for (int i = 0; i < 4; ++i)
#pragma unroll
    for (int j = 0; j < 4; ++j)
      acc[i][j] = *(const f32x4*)(bi + (i * 4 + j) * 256 + lane * 4);

  // V^T into LDS (zero-pad cols 49..63)
  for (int e = lane; e < 512; e += 64) {
    int d = e >> 4, n = 49 + (e & 15);
    VT[d * 72 + n] = 0;
  }
  for (int e = lane; e < 1568; e += 64) {
    int n = e >> 5, d = e & 31;
    VT[d * 72 + n] = vh[e];
  }

  // Q/K fragments straight from global (rows >=49 read garbage; masked below)
  s16x8 aq[4], bk[4];
#pragma unroll
  for (int i = 0; i < 4; ++i)
    aq[i] = *(const s16x8*)(qh + (i * 16 + l15) * 32 + quad * 8);
#pragma unroll
  for (int j = 0; j < 4; ++j)
    bk[j] = *(const s16x8*)(kh + (j * 16 + l15) * 32 + quad * 8);
#pragma unroll
  for (int i = 0; i < 4; ++i)
#pragma unroll
    for (int j = 0; j < 4; ++j)
      acc[i][j] = __builtin_amdgcn_mfma_f32_16x16x32_bf16(aq[i], bk[j], acc[i][j], 0, 0, 0);

  // p = (s*SCALE)^2, mask cols>=49, row sums, write P (unnormalized, bf16)
  const float SC = 0.17677669529663687f;
  float inv[4][4];
#pragma unroll
  for (int i = 0; i < 4; ++i) {
#pragma unroll
    for (int r = 0; r < 4; ++r) {
      int row = i * 16 + quad * 4 + r;
      float rs = 0.f;
#pragma unroll
      for (int j = 0; j < 4; ++j) {
        int col = j * 16 + l15;
        float s = acc[i][j][r] * SC;
        float p = s * s;
        p = (col < 49) ? p : 0.f;
        rs += p;
        P[row * 72 + col] = f2bf(p);
      }
      rs += __shfl_xor(rs, 1);
      rs += __shfl_xor(rs, 2);
      rs += __shfl_xor(rs, 4);
      rs += __shfl_xor(rs, 8);
      inv[i][r] = 1.0f / (rs + 1e-6f);
    }
  }

  // PV: O[n][d] = sum_m P[n][m] * V[m][d]
  s16x8 bvf[2][2];
#pragma unroll
  for (int nn = 0; nn < 2; ++nn)
#pragma unroll
    for (int kk = 0; kk < 2; ++kk)
      bvf[nn][kk] = *(const s16x8*)(VT + (nn * 16 + l15) * 72 + kk * 32 + quad * 8);
  f32x4 oa[4][2] = {};
#pragma unroll
  for (int i = 0; i < 4; ++i)
#pragma unroll
    for (int kk = 0; kk < 2; ++kk) {
      s16x8 ap = *(const s16x8*)(P + (i * 16 + l15) * 72 + kk * 32 + quad * 8);
#pragma unroll
      for (int nn = 0; nn < 2; ++nn)
        oa[i][nn] = __builtin_amdgcn_mfma_f32_16x16x32_bf16(ap, bvf[nn][kk], oa[i][nn], 0, 0, 0);
    }

  // epilogue: normalize rows, store O [B*49, 384] bf16
  const size_t obase = (size_t)b * 49 * 384 + head * 32;
#pragma unroll
  for (int i = 0; i < 4; ++i)
#pragma unroll
    for (int r = 0; r < 4; ++r) {
      int n = i * 16 + quad * 4 + r;
      if (n < 49) {
#pragma unroll
        for (int nn = 0; nn < 2; ++nn) {
          float val = oa[i][nn][r] * inv[i][r];
          O[obase + (size_t)n * 384 + nn * 16 + l15] = f2bf(val);
        }
      }
    }
}

// ---------------- kernel 5: proj GEMM [200704,384] @ [384,384] + bias ----------------
__global__ __launch_bounds__(256) void gemm_proj(const short* __restrict__ A,
                                                 const short* __restrict__ Bt,
                                                 const float* __restrict__ bias,
                                                 float* __restrict__ out) {
  __shared__ __align__(16) short As[2][128 * 32];
  __shared__ __align__(16) short Bs[2][128 * 32];
  const int t = threadIdx.x;
  const int wave = t >> 6, lane = t & 63;
  const int quad = lane >> 4, l15 = lane & 15;
  const int wm = wave & 1, wn = wave >> 1;
  const int m0 = blockIdx.y * 128;
  const int n0 = blockIdx.x * 128;

  auto stage = [&](int buf, int kt) {
#pragma unroll
    for (int p = 0; p < 2; ++p) {
      int o = p * 4096 + wave * 1024 + lane * 16;
      int row = o >> 6, colb = o & 63;
      load16_to_lds((const char*)A + (size_t)(m0 + row) * 768 + kt * 64 + colb,
                    (char*)(&As[buf][0]) + o);
      load16_to_lds((const char*)Bt + (size_t)(n0 + row) * 768 + kt * 64 + colb,
                    (char*)(&Bs[buf][0]) + o);
    }
  };

  f32x4 acc[4][4] = {};
  stage(0, 0);
  for (int kt = 0; kt < 12; ++kt) {
    __syncthreads();
    if (kt + 1 < 12) stage((kt + 1) & 1, kt + 1);
    const short* as = &As[kt & 1][0];
    const short* bs = &Bs[kt & 1][0];
    s16x8 af[4], bfr[4];
#pragma unroll
    for (int i = 0; i < 4; ++i)
      af[i] = *(const s16x8*)(as + (wm * 64 + i * 16 + l15) * 32 + quad * 8);
#pragma unroll
    for (int j = 0; j < 4; ++j)
      bfr[j] = *(const s16x8*)(bs + (wn * 64 + j * 16 + l15) * 32 + quad * 8);
#pragma unroll
    for (int i = 0; i < 4; ++i)
#pragma unroll
      for (int j = 0; j < 4; ++j)
        acc[i][j] = __builtin_amdgcn_mfma_f32_16x16x32_bf16(af[i], bfr[j], acc[i][j], 0, 0, 0);
  }

  const int cb = n0 + wn * 64 + l15;
  float bj[4];
#pragma unroll
  for (int j = 0; j < 4; ++j) bj[j] = bias[cb + j * 16];
#pragma unroll
  for (int i = 0; i < 4; ++i) {
#pragma unroll
    for (int r = 0; r < 4; ++r) {
      int m = m0 + wm * 64 + i * 16 + quad * 4 + r;
      float* orow = out + (size_t)m * 384;
#pragma unroll
      for (int j = 0; j < 4; ++j)
        orow[cb + j * 16] = acc[i][j][r] + bj[j];
    }
  }
}

extern "C" void kernel_launch(void* const* d_in, const int* in_sizes, int n_in,
                              void* d_out, int out_size, void* d_ws, size_t ws_size,
                              hipStream_t stream) {
  const float* x      = (const float*)d_in[0];
  const float* w_qkv  = (const float*)d_in[1];
  const float* w_proj = (const float*)d_in[2];
  const float* b_proj = (const float*)d_in[3];
  const float* btab   = (const float*)d_in[4];
  const int*   rel    = (const int*)d_in[5];

  char* ws = (char*)d_ws;
  short* xb   = (short*)(ws);                       // x bf16, later aliased by O
  short* q    = (short*)(ws + 154140672);
  short* k    = (short*)(ws + 308281344);
  short* v    = (short*)(ws + 462422016);
  short* wqt  = (short*)(ws + 616562688);
  short* wpt  = (short*)(ws + 617447424);
  float* bini = (float*)(ws + 617742336);

  convert_x<<<37632, 256, 0, stream>>>(x, xb);
  prep<<<2496, 256, 0, stream>>>(w_qkv, w_proj, btab, rel, wqt, wpt, bini);
  gemm_qkv<<<dim3(9, 1568), 256, 0, stream>>>(xb, wqt, q, k, v);
  attn<<<12288, 256, 0, stream>>>(q, k, v, bini, xb);
  gemm_proj<<<dim3(3, 1568), 256, 0, stream>>>(xb, wpt, b_proj, (float*)d_out);
}